// Round 4
// baseline (439.274 us; speedup 1.0000x reference)
//
#include <hip/hip_runtime.h>
#include <hip/hip_bf16.h>
#include <math.h>

#define B_ 512
#define N_ 32
#define D_ 300
#define R_ 6
#define E_ 256
#define NG_ 50000
#define NS_ 25000

#define KTOT 2100      // 6*300 (Wrel) + 300 (W0)
#define YLD  2112      // Y leading dim (padded to 33*64)
#define XLD  320       // X0H bf16 leading dim
#define PLD  304       // k1b partial leading dim (fp32)
#define NGP  50176     // 784*64 padded cols (global head)
#define NSP  25088     // 392*64 padded cols (sense head)
#define NCBG 784
#define NCBS 392
#define KP2  320       // padded K for classifier GEMMs

typedef __attribute__((ext_vector_type(8))) short short8;
typedef __attribute__((ext_vector_type(4))) float f32x4;

__device__ __forceinline__ unsigned short f2bf(float f) {
  __hip_bfloat16 h = __float2bfloat16(f);
  return *reinterpret_cast<unsigned short*>(&h);
}

// ---------------- K1a: collapse graph to Y[b, 2112] (fp32 or bf16 out) ----------------
template<int BF>
__global__ __launch_bounds__(256) void k1a_coef_y(
    const float* __restrict__ x, const int* __restrict__ ei,
    const int* __restrict__ et, void* __restrict__ Yv)
{
  int b = blockIdx.x;
  int tid = threadIdx.x;
  __shared__ int srcs[E_], dsts[E_], ets[E_];
  __shared__ int degc[R_*N_];
  __shared__ float coef[R_*N_];

  srcs[tid] = ei[b*2*E_ + tid];
  dsts[tid] = ei[b*2*E_ + E_ + tid];
  ets[tid]  = et[b*E_ + tid];
  if (tid < R_*N_) { degc[tid] = 0; coef[tid] = 0.0f; }
  __syncthreads();

  atomicAdd(&degc[ets[tid]*N_ + dsts[tid]], 1);
  __syncthreads();

  if (dsts[tid] == 0) {
    int r = ets[tid];
    float ds = 1.0f + (float)degc[r*N_ + srcs[tid]];
    float dd = 1.0f + (float)degc[r*N_ + 0];
    atomicAdd(&coef[r*N_ + srcs[tid]], rsqrtf(ds*dd));
  }
  if (tid < R_) {
    atomicAdd(&coef[tid*N_ + 0], 1.0f/(1.0f + (float)degc[tid*N_]));
  }
  __syncthreads();

  const float* xb = x + (size_t)b*N_*D_;
  float* Yf = (float*)Yv + (size_t)b*YLD;
  unsigned short* Yb = (unsigned short*)Yv + (size_t)b*YLD;
  for (int k = tid; k < D_; k += 256) {
    #pragma unroll
    for (int r = 0; r < R_; ++r) {
      float acc = 0.0f;
      for (int n = 0; n < N_; ++n) {
        float c = coef[r*N_ + n];          // uniform across threads
        if (c != 0.0f) acc += c * xb[n*D_ + k];
      }
      if constexpr (BF) Yb[r*D_ + k] = f2bf(acc); else Yf[r*D_ + k] = acc;
    }
    if constexpr (BF) Yb[6*D_ + k] = f2bf(xb[k]); else Yf[6*D_ + k] = xb[k];
  }
  if (tid < YLD - KTOT) {
    if constexpr (BF) Yb[KTOT + tid] = 0; else Yf[KTOT + tid] = 0.0f;
  }
}

// ---------------- W transpose + bf16: Wt[c][Kpad] from row-major [K][C] ----------------
__global__ __launch_bounds__(256) void wtrans(
    const float* __restrict__ S0, const float* __restrict__ S1, int Ksplit,
    int K, int C, int ldsrc, int Kpad, unsigned short* __restrict__ Wt)
{
  int c = blockIdx.x*256 + threadIdx.x;
  int k0 = blockIdx.y*64;
  for (int kk = 0; kk < 64; kk += 8) {
    unsigned short u[8];
    #pragma unroll
    for (int j = 0; j < 8; ++j) {
      int k = k0 + kk + j;
      float v = 0.f;
      if (c < C && k < K)
        v = (k < Ksplit) ? S0[(size_t)k*ldsrc + c] : S1[(size_t)(k-Ksplit)*ldsrc + c];
      u[j] = f2bf(v);
    }
    *reinterpret_cast<short8*>(&Wt[(size_t)c*Kpad + k0 + kk]) =
        *reinterpret_cast<const short8*>(u);
  }
}

// ---------------- gemm3: M=512 whole, BN=64, BK=64; A bf16 direct-gather, B via LDS ----
// MODE 0: write fp32 partial (z-split over K tiles)
// MODE 1: stats only -> part[row][cb] = (max, sumexp) incl. bias
// MODE 2: write out[row][col] = acc + bias - lse[row]
template<int MODE>
__global__ __launch_bounds__(256, 2) void gemm3(
    const unsigned short* __restrict__ A, int lda,
    const unsigned short* __restrict__ Bt, int ldbt,
    int nkt, int zinc,
    const float* __restrict__ bias, int C,
    float* __restrict__ outp, int ldo,
    float2* __restrict__ part, int ldpart,
    const float* __restrict__ lse, int swz)
{
  __shared__ unsigned short Bs[64*64];

  int cb, z;
  if constexpr (MODE == 0) {
    cb = blockIdx.x % 5; z = blockIdx.x / 5;
  } else {
    int id = blockIdx.x;
    if (swz) { int q = gridDim.x >> 3; id = (id & 7)*q + (id >> 3); }
    cb = id; z = 0;
  }
  const int c0 = cb * 64;

  const int tid = threadIdx.x;
  const int lane = tid & 63, wid = tid >> 6;
  const int lr = lane & 15, lg = lane >> 4;
  const int rowb = wid * 128;

  // B staging mapping: thread -> col sc, k-seg ss (16 k each, 2x short8)
  const int sc = tid >> 2, ss = tid & 3;
  const size_t gB = (size_t)(c0 + sc) * ldbt + ss*16;
  const int lB  = sc*64 + ((ss*16    ) ^ ((sc & 7) << 3));
  const int lB2 = sc*64 + ((ss*16 + 8) ^ ((sc & 7) << 3));

  f32x4 acc[8][4];
  #pragma unroll
  for (int a = 0; a < 8; ++a)
    #pragma unroll
    for (int b = 0; b < 4; ++b) acc[a][b] = (f32x4){0.f,0.f,0.f,0.f};

  int t = (MODE == 0) ? z : 0;
  const int zi = (MODE == 0) ? zinc : 1;

  // prologue: stage tile t
  {
    short8 r0 = *reinterpret_cast<const short8*>(&Bt[gB + (size_t)t*64]);
    short8 r1 = *reinterpret_cast<const short8*>(&Bt[gB + (size_t)t*64 + 8]);
    *reinterpret_cast<short8*>(&Bs[lB])  = r0;
    *reinterpret_cast<short8*>(&Bs[lB2]) = r1;
  }
  __syncthreads();

  while (true) {
    int tn = t + zi;
    bool more = (tn < nkt);
    short8 p0{}, p1{};
    if (more) {
      p0 = *reinterpret_cast<const short8*>(&Bt[gB + (size_t)tn*64]);
      p1 = *reinterpret_cast<const short8*>(&Bt[gB + (size_t)tn*64 + 8]);
    }
    const int kt = t * 64;
    #pragma unroll
    for (int kk = 0; kk < 2; ++kk) {
      short8 bfr[4];
      #pragma unroll
      for (int b = 0; b < 4; ++b)
        bfr[b] = *reinterpret_cast<const short8*>(
            &Bs[(b*16 + lr)*64 + ((kk*32 + lg*8) ^ ((lr & 7) << 3))]);
      #pragma unroll
      for (int a = 0; a < 8; ++a) {
        short8 af = *reinterpret_cast<const short8*>(
            &A[(size_t)(rowb + a*16 + lr)*lda + kt + kk*32 + lg*8]);
        #pragma unroll
        for (int b = 0; b < 4; ++b)
          acc[a][b] = __builtin_amdgcn_mfma_f32_16x16x32_bf16(af, bfr[b], acc[a][b], 0, 0, 0);
      }
    }
    if (!more) break;
    __syncthreads();
    *reinterpret_cast<short8*>(&Bs[lB])  = p0;
    *reinterpret_cast<short8*>(&Bs[lB2]) = p1;
    __syncthreads();
    t = tn;
  }

  // ---- epilogue ----
  if constexpr (MODE == 0) {
    float* o = outp + (size_t)z * (size_t)B_ * ldo;
    #pragma unroll
    for (int a = 0; a < 8; ++a) {
      int row = rowb + a*16 + lg*4;
      #pragma unroll
      for (int b = 0; b < 4; ++b) {
        int col = c0 + b*16 + lr;
        if (col < C) {
          #pragma unroll
          for (int i = 0; i < 4; ++i)
            o[(size_t)(row+i)*ldo + col] = acc[a][b][i];
        }
      }
    }
  } else {
    float bia[4]; bool okc[4];
    #pragma unroll
    for (int b = 0; b < 4; ++b) {
      int col = c0 + b*16 + lr;
      okc[b] = (col < C);
      bia[b] = okc[b] ? bias[col] : 0.f;
    }
    if constexpr (MODE == 1) {
      #pragma unroll
      for (int a = 0; a < 8; ++a) {
        #pragma unroll
        for (int i = 0; i < 4; ++i) {
          float v[4], m = -3.0e38f;
          #pragma unroll
          for (int b = 0; b < 4; ++b) {
            v[b] = okc[b] ? (acc[a][b][i] + bia[b]) : -3.0e38f;
            m = fmaxf(m, v[b]);
          }
          #pragma unroll
          for (int off = 1; off < 16; off <<= 1) m = fmaxf(m, __shfl_xor(m, off));
          float s = 0.f;
          #pragma unroll
          for (int b = 0; b < 4; ++b) s += __expf(v[b] - m);
          #pragma unroll
          for (int off = 1; off < 16; off <<= 1) s += __shfl_xor(s, off);
          if (lr == 0)
            part[(size_t)(rowb + a*16 + lg*4 + i)*ldpart + cb] = make_float2(m, s);
        }
      }
    } else {
      #pragma unroll
      for (int a = 0; a < 8; ++a) {
        #pragma unroll
        for (int i = 0; i < 4; ++i) {
          int row = rowb + a*16 + lg*4 + i;
          float L = lse[row];
          #pragma unroll
          for (int b = 0; b < 4; ++b) {
            int col = c0 + b*16 + lr;
            if (okc[b]) outp[(size_t)row*ldo + col] = acc[a][b][i] + bia[b] - L;
          }
        }
      }
    }
  }
}

// ---------------- K1c: reduce z-partials, leaky, emit bf16 X0H [512][320] ----------------
__global__ __launch_bounds__(256) void k1c_reduce(
    const float* __restrict__ part, int nz, unsigned short* __restrict__ X0Hbf)
{
  int idx = blockIdx.x*256 + threadIdx.x;
  if (idx >= B_*XLD) return;
  int m = idx / XLD, c = idx % XLD;
  float v = 0.f;
  if (c < D_) {
    for (int zz = 0; zz < nz; ++zz) v += part[(size_t)zz*B_*PLD + (size_t)m*PLD + c];
    v = (v >= 0.f) ? v : 0.1f*v;
  }
  X0Hbf[idx] = f2bf(v);
}

// ---------------- K5: combine (m,s) partials -> lse[1024] ----------------
__global__ __launch_bounds__(256) void k5_lse(
    const float2* __restrict__ pg, const float2* __restrict__ ps,
    float* __restrict__ lse)
{
  int row = blockIdx.x;
  const float2* p; int n;
  if (row < B_) { p = pg + (size_t)row*NCBG; n = NCBG; }
  else          { p = ps + (size_t)(row - B_)*NCBS; n = NCBS; }
  float m = -3.0e38f, s = 0.f;
  for (int i = threadIdx.x; i < n; i += 256) {
    float2 v = p[i];
    float mn = fmaxf(m, v.x);
    s = s*__expf(m - mn) + v.y*__expf(v.x - mn);
    m = mn;
  }
  #pragma unroll
  for (int off = 1; off < 64; off <<= 1) {
    float m2 = __shfl_xor(m, off), s2 = __shfl_xor(s, off);
    float mn = fmaxf(m, m2);
    s = s*__expf(m - mn) + s2*__expf(m2 - mn);
    m = mn;
  }
  __shared__ float ms[4], ss2[4];
  int w = threadIdx.x >> 6;
  if ((threadIdx.x & 63) == 0) { ms[w] = m; ss2[w] = s; }
  __syncthreads();
  if (threadIdx.x == 0) {
    float M = ms[0], S = ss2[0];
    #pragma unroll
    for (int ww = 1; ww < 4; ++ww) {
      float mn = fmaxf(M, ms[ww]);
      S = S*__expf(M - mn) + ss2[ww]*__expf(ms[ww] - mn);
      M = mn;
    }
    lse[row] = M + __logf(S);
  }
}

// ================== FALLBACK (round-3 proven path) ==================
template<int ABF16>
__global__ __launch_bounds__(256) void gemm2(
    const void* __restrict__ Av, int lda, int K, int nkt, int Ksplit,
    const float* __restrict__ B0, const float* __restrict__ B1, int ldb, int C,
    const float* __restrict__ bias, float* __restrict__ out, int ldo, int zstride,
    int nmb, int ncb, int nz, int swz)
{
  __shared__ unsigned short As[256*72];
  __shared__ unsigned short Bs[64*72];

  int id = blockIdx.x;
  if (swz) {
    int nwg = gridDim.x;
    int q = nwg >> 3, r = nwg & 7;
    int xcd = id & 7, loc = id >> 3;
    id = (xcd < r ? xcd*(q+1) : r*(q+1) + (xcd-r)*q) + loc;
  }
  const int plane = nmb * ncb;
  const int z  = id / plane;
  const int r2 = id % plane;
  const int mb = r2 % nmb;
  const int cb = r2 / nmb;
  const int m0 = mb * 256;
  const int c0 = cb * 64;

  const int tid = threadIdx.x;
  const int lane = tid & 63, wid = tid >> 6;
  const int lr = lane & 15, lg = lane >> 4;

  f32x4 acc[4][4];
  #pragma unroll
  for (int a = 0; a < 4; ++a)
    #pragma unroll
    for (int b = 0; b < 4; ++b) acc[a][b] = (f32x4){0.f, 0.f, 0.f, 0.f};

  for (int t = z; t < nkt; t += nz) {
    const int kt = t * 64;
    __syncthreads();
    if constexpr (ABF16) {
      const unsigned short* A = (const unsigned short*)Av;
      const int s = tid & 7, r0 = tid >> 3;
      #pragma unroll
      for (int p = 0; p < 8; ++p) {
        int row = r0 + p*32;
        short8 v = *reinterpret_cast<const short8*>(&A[(size_t)(m0+row)*lda + kt + s*8]);
        *reinterpret_cast<short8*>(&As[row*72 + s*8]) = v;
      }
    } else {
      const float* A = (const float*)Av;
      const int s = tid & 15, r0 = tid >> 4;
      #pragma unroll
      for (int p = 0; p < 16; ++p) {
        int row = r0 + p*16;
        float4 v = *reinterpret_cast<const float4*>(&A[(size_t)(m0+row)*lda + kt + s*4]);
        ushort4 u;
        u.x = f2bf(v.x); u.y = f2bf(v.y); u.z = f2bf(v.z); u.w = f2bf(v.w);
        *reinterpret_cast<ushort4*>(&As[row*72 + s*4]) = u;
      }
    }
    {
      const int c4 = tid & 15, kr = tid >> 4;
      #pragma unroll
      for (int p = 0; p < 4; ++p) {
        int k = kt + p*16 + kr;
        float4 v = make_float4(0.f, 0.f, 0.f, 0.f);
        if (k < K && c0 + c4*4 + 4 <= C) {
          const float* brow = (k < Ksplit) ? (B0 + (size_t)k*ldb)
                                           : (B1 + (size_t)(k-Ksplit)*ldb);
          v = *reinterpret_cast<const float4*>(&brow[c0 + c4*4]);
        }
        int kk = p*16 + kr;
        Bs[(c4*4+0)*72 + kk] = f2bf(v.x);
        Bs[(c4*4+1)*72 + kk] = f2bf(v.y);
        Bs[(c4*4+2)*72 + kk] = f2bf(v.z);
        Bs[(c4*4+3)*72 + kk] = f2bf(v.w);
      }
    }
    __syncthreads();
    const unsigned short* Ab = &As[(wid*64 + lr)*72 + lg*8];
    const unsigned short* Bb = &Bs[lr*72 + lg*8];
    #pragma unroll
    for (int kk = 0; kk < 2; ++kk) {
      short8 af[4], bfr[4];
      #pragma unroll
      for (int a = 0; a < 4; ++a)
        af[a] = *reinterpret_cast<const short8*>(Ab + a*16*72 + kk*32);
      #pragma unroll
      for (int b = 0; b < 4; ++b)
        bfr[b] = *reinterpret_cast<const short8*>(Bb + b*16*72 + kk*32);
      #pragma unroll
      for (int a = 0; a < 4; ++a)
        #pragma unroll
        for (int b = 0; b < 4; ++b)
          acc[a][b] = __builtin_amdgcn_mfma_f32_16x16x32_bf16(af[a], bfr[b], acc[a][b], 0, 0, 0);
    }
  }

  float* o = out + (size_t)z * zstride;
  #pragma unroll
  for (int a = 0; a < 4; ++a) {
    int row = m0 + wid*64 + a*16 + lg*4;
    #pragma unroll
    for (int b = 0; b < 4; ++b) {
      int col = c0 + b*16 + lr;
      if (col < C) {
        float bv = bias ? bias[col] : 0.f;
        #pragma unroll
        for (int i = 0; i < 4; ++i)
          o[(size_t)(row+i)*ldo + col] = acc[a][b][i] + bv;
      }
    }
  }
}

__global__ __launch_bounds__(256) void k3_lse(
    const float* __restrict__ out, float* __restrict__ lse)
{
  int row = blockIdx.x;
  const float* p; int C;
  if (row < B_) { p = out + (size_t)row*NG_; C = NG_; }
  else          { p = out + (size_t)B_*NG_ + (size_t)(row - B_)*NS_; C = NS_; }

  float m = -1e30f, s = 0.0f;
  for (int i = threadIdx.x; i < C; i += 256) {
    float v = p[i];
    float mn = fmaxf(m, v);
    s = s*__expf(m - mn) + __expf(v - mn);
    m = mn;
  }
  #pragma unroll
  for (int off = 32; off > 0; off >>= 1) {
    float m2 = __shfl_xor(m, off);
    float s2 = __shfl_xor(s, off);
    float mn = fmaxf(m, m2);
    s = s*__expf(m - mn) + s2*__expf(m2 - mn);
    m = mn;
  }
  __shared__ float ms[4], ss[4];
  int wid = threadIdx.x >> 6;
  if ((threadIdx.x & 63) == 0) { ms[wid] = m; ss[wid] = s; }
  __syncthreads();
  if (threadIdx.x == 0) {
    float M = ms[0], S = ss[0];
    #pragma unroll
    for (int w = 1; w < 4; ++w) {
      float mn = fmaxf(M, ms[w]);
      S = S*__expf(M - mn) + ss[w]*__expf(ms[w] - mn);
      M = mn;
    }
    lse[row] = M + __logf(S);
  }
}

__global__ void k4_sub(float* __restrict__ out, const float* __restrict__ lse)
{
  const size_t g4 = (size_t)B_*NG_/4;
  const size_t total4 = g4 + (size_t)B_*NS_/4;
  size_t stride = (size_t)gridDim.x * blockDim.x;
  for (size_t i4 = (size_t)blockIdx.x*blockDim.x + threadIdx.x; i4 < total4; i4 += stride) {
    int row;
    if (i4 < g4) row = (int)(i4 / (NG_/4));
    else         row = B_ + (int)((i4 - g4) / (NS_/4));
    float l = lse[row];
    float4 v = reinterpret_cast<float4*>(out)[i4];
    v.x -= l; v.y -= l; v.z -= l; v.w -= l;
    reinterpret_cast<float4*>(out)[i4] = v;
  }
}

// =====================================================================
extern "C" void kernel_launch(void* const* d_in, const int* in_sizes, int n_in,
                              void* d_out, int out_size, void* d_ws, size_t ws_size,
                              hipStream_t stream)
{
  const float* x    = (const float*)d_in[0];
  const int*   ei   = (const int*)  d_in[1];
  const int*   et   = (const int*)  d_in[2];
  const float* Wrel = (const float*)d_in[3];
  const float* W0   = (const float*)d_in[4];
  const float* Wg   = (const float*)d_in[5];
  const float* bg   = (const float*)d_in[6];
  const float* Ws   = (const float*)d_in[7];
  const float* bs   = (const float*)d_in[8];
  float* out = (float*)d_out;

  // --- new-path ws layout (bytes) ---
  const size_t sz_wtg = (size_t)NGP*KP2*2;       // 32,112,640
  const size_t sz_wts = (size_t)NSP*KP2*2;       // 16,056,320
  const size_t sz_wt1 = (size_t)512*YLD*2;       //  2,162,688
  const size_t sz_y   = (size_t)B_*YLD*2;        //  2,162,688
  const size_t sz_x0  = (size_t)B_*XLD*2;        //    327,680
  const size_t sz_p1  = (size_t)8*B_*PLD*4;      //  4,980,736
  const size_t sz_pg  = (size_t)B_*NCBG*8;       //  3,211,264
  const size_t sz_ps  = (size_t)B_*NCBS*8;       //  1,605,632
  const size_t sz_lse = 4096;
  const size_t NEED = sz_wtg+sz_wts+sz_wt1+sz_y+sz_x0+sz_p1+sz_pg+sz_ps+sz_lse;

  if (ws_size >= NEED) {
    char* p = (char*)d_ws;
    unsigned short* Wtg = (unsigned short*)p;           p += sz_wtg;
    unsigned short* Wts = (unsigned short*)p;           p += sz_wts;
    unsigned short* Wt1 = (unsigned short*)p;           p += sz_wt1;
    unsigned short* Ybf = (unsigned short*)p;           p += sz_y;
    unsigned short* X0H = (unsigned short*)p;           p += sz_x0;
    float*  P1   = (float*)p;                           p += sz_p1;
    float2* Pg   = (float2*)p;                          p += sz_pg;
    float2* Ps   = (float2*)p;                          p += sz_ps;
    float*  LSE  = (float*)p;

    k1a_coef_y<1><<<B_, 256, 0, stream>>>(x, ei, et, Ybf);
    wtrans<<<dim3(NGP/256, KP2/64), 256, 0, stream>>>(Wg, Wg, D_, D_, NG_, NG_, KP2, Wtg);
    wtrans<<<dim3(NSP/256, KP2/64), 256, 0, stream>>>(Ws, Ws, D_, D_, NS_, NS_, KP2, Wts);
    wtrans<<<dim3(2, YLD/64), 256, 0, stream>>>(Wrel, W0, 6*D_, KTOT, D_, D_, YLD, Wt1);

    // k1b: 5 cb x 8 z blocks, partial fp32
    gemm3<0><<<40, 256, 0, stream>>>(Ybf, YLD, Wt1, YLD, 33, 8,
                                     nullptr, D_, P1, PLD, nullptr, 0, nullptr, 0);
    k1c_reduce<<<(B_*XLD + 255)/256, 256, 0, stream>>>(P1, 8, X0H);

    // pass1: stats
    gemm3<1><<<NCBG, 256, 0, stream>>>(X0H, XLD, Wtg, KP2, 5, 1,
                                       bg, NG_, nullptr, 0, Pg, NCBG, nullptr, 1);
    gemm3<1><<<NCBS, 256, 0, stream>>>(X0H, XLD, Wts, KP2, 5, 1,
                                       bs, NS_, nullptr, 0, Ps, NCBS, nullptr, 1);
    k5_lse<<<2*B_, 256, 0, stream>>>(Pg, Ps, LSE);

    // pass2: write out - lse
    gemm3<2><<<NCBG, 256, 0, stream>>>(X0H, XLD, Wtg, KP2, 5, 1,
                                       bg, NG_, out, NG_, nullptr, 0, LSE, 1);
    gemm3<2><<<NCBS, 256, 0, stream>>>(X0H, XLD, Wts, KP2, 5, 1,
                                       bs, NS_, out + (size_t)B_*NG_, NS_, nullptr, 0,
                                       LSE + B_, 1);
  } else {
    // -------- fallback: proven round-3 path --------
    float* wsf = (float*)d_ws;
    float* Y = wsf;
    size_t off = (size_t)B_*YLD;
    unsigned short* X0Hbf = (unsigned short*)(wsf + off);
    off += (size_t)B_*XLD/2;
    float* LSE = wsf + off;
    off += 1024;
    float* PART = wsf + off;
    size_t remain = (ws_size/4 > off) ? ws_size/4 - off : 0;
    int nz = 8;
    while (nz > 1 && (size_t)nz*B_*PLD > remain) nz >>= 1;

    k1a_coef_y<0><<<B_, 256, 0, stream>>>(x, ei, et, Y);
    gemm2<0><<<2*5*nz, 256, 0, stream>>>(
        Y, YLD, KTOT, 33, 6*D_, Wrel, W0, D_, D_,
        nullptr, PART, PLD, B_*PLD, 2, 5, nz, 0);
    k1c_reduce<<<(B_*XLD + 255)/256, 256, 0, stream>>>(PART, nz, X0Hbf);
    gemm2<1><<<2*782, 256, 0, stream>>>(
        X0Hbf, XLD, D_, 5, D_, Wg, Wg, NG_, NG_, bg, out, NG_, 0, 2, 782, 1, 1);
    gemm2<1><<<2*391, 256, 0, stream>>>(
        X0Hbf, XLD, D_, 5, D_, Ws, Ws, NS_, NS_, bs, out + (size_t)B_*NG_, NS_, 0, 2, 391, 1, 1);
    k3_lse<<<2*B_, 256, 0, stream>>>(out, LSE);
    k4_sub<<<2048, 256, 0, stream>>>(out, LSE);
  }
}

// Round 5
// 272.859 us; speedup vs baseline: 1.6099x; 1.6099x over previous
//
#include <hip/hip_runtime.h>
#include <hip/hip_bf16.h>
#include <math.h>

#define B_ 512
#define N_ 32
#define D_ 300
#define R_ 6
#define E_ 256
#define NG_ 50000
#define NS_ 25000

#define KTOT 2100      // 6*300 (Wrel) + 300 (W0)
#define YLD  2112      // Y bf16 leading dim (33*64)
#define XLD  320       // X0H bf16 leading dim (5*64)
#define PLD  304       // k1b partial leading dim (fp32)
#define NCBG 782       // ceil(50000/64)
#define NCBS 391       // ceil(25000/64)

typedef __attribute__((ext_vector_type(8))) short short8;
typedef __attribute__((ext_vector_type(4))) float f32x4;

__device__ __forceinline__ unsigned short f2bf(float f) {
  __hip_bfloat16 h = __float2bfloat16(f);
  return *reinterpret_cast<unsigned short*>(&h);
}

__device__ __forceinline__ void gload_lds16(const unsigned short* g, unsigned short* l) {
  __builtin_amdgcn_global_load_lds(
      (const __attribute__((address_space(1))) void*)g,
      (__attribute__((address_space(3))) void*)l,
      16, 0, 0);
}

// ---------------- K1a: collapse graph to Y[b, 2112] bf16 (zero k-pad) ----------------
__global__ __launch_bounds__(256) void k1a_coef_y(
    const float* __restrict__ x, const int* __restrict__ ei,
    const int* __restrict__ et, unsigned short* __restrict__ Y)
{
  int b = blockIdx.x;
  int tid = threadIdx.x;
  __shared__ int srcs[E_], dsts[E_], ets[E_];
  __shared__ int degc[R_*N_];
  __shared__ float coef[R_*N_];

  srcs[tid] = ei[b*2*E_ + tid];
  dsts[tid] = ei[b*2*E_ + E_ + tid];
  ets[tid]  = et[b*E_ + tid];
  if (tid < R_*N_) { degc[tid] = 0; coef[tid] = 0.0f; }
  __syncthreads();

  atomicAdd(&degc[ets[tid]*N_ + dsts[tid]], 1);
  __syncthreads();

  if (dsts[tid] == 0) {
    int r = ets[tid];
    float ds = 1.0f + (float)degc[r*N_ + srcs[tid]];
    float dd = 1.0f + (float)degc[r*N_ + 0];
    atomicAdd(&coef[r*N_ + srcs[tid]], rsqrtf(ds*dd));
  }
  if (tid < R_) {
    atomicAdd(&coef[tid*N_ + 0], 1.0f/(1.0f + (float)degc[tid*N_]));
  }
  __syncthreads();

  const float* xb = x + (size_t)b*N_*D_;
  unsigned short* Yb = Y + (size_t)b*YLD;
  for (int k = tid; k < D_; k += 256) {
    #pragma unroll
    for (int r = 0; r < R_; ++r) {
      float acc = 0.0f;
      for (int n = 0; n < N_; ++n) {
        float c = coef[r*N_ + n];          // uniform across threads
        if (c != 0.0f) acc += c * xb[n*D_ + k];
      }
      Yb[r*D_ + k] = f2bf(acc);
    }
    Yb[6*D_ + k] = f2bf(xb[k]);            // x[b,0,:] for the W0 term
  }
  if (tid < YLD - KTOT) Yb[KTOT + tid] = 0;
}

// ---------------- gemm4: BM=256, BN=64, BK=64, 4 waves (64 rows each) ----------------
// A: bf16, staged via global_load_lds (linear LDS, pre-swizzled source).
// B: fp32 W rows, reg-gathered per column octet, swizzled ds_write_b128.
// MODE 0: k1b  (z-split partials -> P1;  B = [Wrel;W0], Ksplit=1800)
// MODE 1: heads (logits+bias -> out, per-block (max,sumexp) -> part)
template<int MODE>
__global__ __launch_bounds__(256, 3) void gemm4(
    const unsigned short* __restrict__ A, int lda,
    const float* __restrict__ B0, const float* __restrict__ B1,
    const float* __restrict__ bias0, const float* __restrict__ bias1,
    float* __restrict__ out0, float* __restrict__ out1,
    float2* __restrict__ part0, float2* __restrict__ part1,
    float* __restrict__ P1, int nz)
{
  __shared__ unsigned short As[256*64];   // [row][k] linear, swizzled slots
  __shared__ unsigned short Bs[64*80];    // [col][k] stride 80, swizzled slots

  const int tid  = threadIdx.x;
  const int lane = tid & 63, wid = tid >> 6;
  const int lr = lane & 15, lg = lane >> 4;

  int m0, c0, cb = 0, z = 0;
  int t_beg, t_step, t_end;
  const float *Bq0 = nullptr, *Bq1 = nullptr, *bias = nullptr;
  float* outp = nullptr; float2* part = nullptr;
  int ksplit, ldB, Kk, C, ldo = 0, ldpart = 0;

  if constexpr (MODE == 0) {
    int id = blockIdx.x;          // 2 mb * 5 cb * nz
    int mb = id & 1; id >>= 1;
    cb = id % 5; z = id / 5;
    m0 = mb*256; c0 = cb*64;
    t_beg = z; t_step = nz; t_end = 33;
    Bq0 = B0; Bq1 = B1; ksplit = 6*D_; ldB = D_; Kk = KTOT; C = D_;
  } else {
    int nwg = gridDim.x;          // 2*(NCBG+NCBS)
    int id = blockIdx.x;
    { int q = nwg >> 3, r = nwg & 7, xcd = id & 7, loc = id >> 3;
      id = (xcd < r ? xcd*(q+1) : r*(q+1) + (xcd-r)*q) + loc; }
    bool hg = (id < 2*NCBG);
    int hid = hg ? id : id - 2*NCBG;
    int mb = hid & 1; cb = hid >> 1;     // mb fastest: pair shares col-block/XCD
    m0 = mb*256; c0 = cb*64;
    t_beg = 0; t_step = 1; t_end = 5;
    ksplit = 1<<30; Kk = D_;
    if (hg) { Bq0 = B0; bias = bias0; outp = out0; part = part0;
              C = NG_; ldB = NG_; ldo = NG_; ldpart = NCBG; }
    else    { Bq0 = B1; bias = bias1; outp = out1; part = part1;
              C = NS_; ldB = NS_; ldo = NS_; ldpart = NCBS; }
  }

  // staging maps
  const int r8 = lane >> 3, sl = lane & 7;     // A: row-in-chunk, 16B slot
  const int c_l = tid & 63, ob = tid >> 6;     // B: column, octet base
  const int gcol = c0 + c_l;
  const bool cok = (gcol < C);

  f32x4 acc[4][4];
  #pragma unroll
  for (int a = 0; a < 4; ++a)
    #pragma unroll
    for (int b = 0; b < 4; ++b) acc[a][b] = (f32x4){0.f,0.f,0.f,0.f};

  for (int t = t_beg; t < t_end; t += t_step) {
    const int kt = t * 64;
    __syncthreads();   // previous tile's readers done

    // ---- A: 8 async DMA per wave, pre-swizzled source, linear dest ----
    #pragma unroll
    for (int i = 0; i < 8; ++i) {
      int row_l = wid*64 + i*8 + r8;
      int sslot = sl ^ (row_l & 7);
      const unsigned short* g = A + (size_t)(m0 + row_l)*lda + kt + sslot*8;
      gload_lds16(g, &As[(wid*64 + i*8)*64]);
    }

    // ---- B: gather 2 octets (8 k each) per thread, swizzled b128 writes ----
    #pragma unroll
    for (int it = 0; it < 2; ++it) {
      int o  = ob + it*4;
      int kb = kt + o*8;
      float f[8];
      #pragma unroll
      for (int j = 0; j < 8; ++j) {
        int k = kb + j;
        float v = 0.f;
        if (cok && k < Kk)
          v = (k < ksplit) ? Bq0[(size_t)k*ldB + gcol]
                           : Bq1[(size_t)(k - ksplit)*ldB + gcol];
        f[j] = v;
      }
      unsigned short u[8];
      #pragma unroll
      for (int j = 0; j < 8; ++j) u[j] = f2bf(f[j]);
      *reinterpret_cast<short8*>(&Bs[c_l*80 + ((o ^ (c_l & 7)) << 3)]) =
          *reinterpret_cast<const short8*>(u);
    }

    __syncthreads();   // drains vmcnt (DMA) + lgkm (ds_writes)

    // ---- MFMA over the 64-k tile ----
    #pragma unroll
    for (int kk = 0; kk < 2; ++kk) {
      const int q = kk*4 + lg;
      short8 bfr[4];
      #pragma unroll
      for (int b = 0; b < 4; ++b) {
        int col = b*16 + lr;
        bfr[b] = *reinterpret_cast<const short8*>(&Bs[col*80 + ((q ^ (col & 7)) << 3)]);
      }
      #pragma unroll
      for (int a = 0; a < 4; ++a) {
        int row = wid*64 + a*16 + lr;
        short8 af = *reinterpret_cast<const short8*>(&As[row*64 + ((q ^ (row & 7)) << 3)]);
        #pragma unroll
        for (int b = 0; b < 4; ++b)
          acc[a][b] = __builtin_amdgcn_mfma_f32_16x16x32_bf16(af, bfr[b], acc[a][b], 0, 0, 0);
      }
    }
  }

  // ---- epilogue ----
  if constexpr (MODE == 0) {
    float* o = P1 + (size_t)z * (size_t)B_ * PLD;
    #pragma unroll
    for (int a = 0; a < 4; ++a) {
      int row = m0 + wid*64 + a*16 + lg*4;
      #pragma unroll
      for (int b = 0; b < 4; ++b) {
        int col = c0 + b*16 + lr;
        if (col < C) {
          #pragma unroll
          for (int i = 0; i < 4; ++i)
            o[(size_t)(row + i)*PLD + col] = acc[a][b][i];
        }
      }
    }
  } else {
    float bia[4]; bool okc[4];
    #pragma unroll
    for (int b = 0; b < 4; ++b) {
      int col = c0 + b*16 + lr;
      okc[b] = (col < C);
      bia[b] = okc[b] ? bias[col] : 0.f;
    }
    #pragma unroll
    for (int a = 0; a < 4; ++a) {
      #pragma unroll
      for (int i = 0; i < 4; ++i) {
        int row = m0 + wid*64 + a*16 + lg*4 + i;
        float v[4], mx = -3.0e38f;
        #pragma unroll
        for (int b = 0; b < 4; ++b) {
          v[b] = okc[b] ? (acc[a][b][i] + bia[b]) : -3.0e38f;
          mx = fmaxf(mx, v[b]);
        }
        #pragma unroll
        for (int b = 0; b < 4; ++b)
          if (okc[b]) outp[(size_t)row*ldo + c0 + b*16 + lr] = v[b];
        #pragma unroll
        for (int off = 1; off < 16; off <<= 1) mx = fmaxf(mx, __shfl_xor(mx, off));
        float s = 0.f;
        #pragma unroll
        for (int b = 0; b < 4; ++b) s += __expf(v[b] - mx);
        #pragma unroll
        for (int off = 1; off < 16; off <<= 1) s += __shfl_xor(s, off);
        if (lr == 0) part[(size_t)row*ldpart + cb] = make_float2(mx, s);
      }
    }
  }
}

// ---------------- K1c: reduce z-partials, leaky, emit bf16 X0H [512][320] ----------------
__global__ __launch_bounds__(256) void k1c_reduce(
    const float* __restrict__ part, int nz, unsigned short* __restrict__ X0Hbf)
{
  int idx = blockIdx.x*256 + threadIdx.x;
  if (idx >= B_*XLD) return;
  int m = idx / XLD, c = idx % XLD;
  float v = 0.f;
  if (c < D_) {
    for (int zz = 0; zz < nz; ++zz) v += part[(size_t)zz*B_*PLD + (size_t)m*PLD + c];
    v = (v >= 0.f) ? v : 0.1f*v;
  }
  X0Hbf[idx] = f2bf(v);
}

// ---------------- K5: combine (m,s) partials -> lse[1024] ----------------
__global__ __launch_bounds__(256) void k5_lse(
    const float2* __restrict__ pg, const float2* __restrict__ ps,
    float* __restrict__ lse)
{
  int row = blockIdx.x;
  const float2* p; int n;
  if (row < B_) { p = pg + (size_t)row*NCBG; n = NCBG; }
  else          { p = ps + (size_t)(row - B_)*NCBS; n = NCBS; }
  float m = -3.0e38f, s = 0.f;
  for (int i = threadIdx.x; i < n; i += 256) {
    float2 v = p[i];
    float mn = fmaxf(m, v.x);
    s = s*__expf(m - mn) + v.y*__expf(v.x - mn);
    m = mn;
  }
  #pragma unroll
  for (int off = 1; off < 64; off <<= 1) {
    float m2 = __shfl_xor(m, off), s2 = __shfl_xor(s, off);
    float mn = fmaxf(m, m2);
    s = s*__expf(m - mn) + s2*__expf(m2 - mn);
    m = mn;
  }
  __shared__ float ms[4], ss2[4];
  int w = threadIdx.x >> 6;
  if ((threadIdx.x & 63) == 0) { ms[w] = m; ss2[w] = s; }
  __syncthreads();
  if (threadIdx.x == 0) {
    float M = ms[0], S = ss2[0];
    #pragma unroll
    for (int ww = 1; ww < 4; ++ww) {
      float mn = fmaxf(M, ms[ww]);
      S = S*__expf(M - mn) + ss2[ww]*__expf(ms[ww] - mn);
      M = mn;
    }
    lse[row] = M + __logf(S);
  }
}

// ---------------- K4: out -= lse[row], float4 ----------------
__global__ void k4_sub(float* __restrict__ out, const float* __restrict__ lse)
{
  const size_t g4 = (size_t)B_*NG_/4;
  const size_t total4 = g4 + (size_t)B_*NS_/4;
  size_t stride = (size_t)gridDim.x * blockDim.x;
  for (size_t i4 = (size_t)blockIdx.x*blockDim.x + threadIdx.x; i4 < total4; i4 += stride) {
    int row;
    if (i4 < g4) row = (int)(i4 / (NG_/4));
    else         row = B_ + (int)((i4 - g4) / (NS_/4));
    float l = lse[row];
    float4 v = reinterpret_cast<float4*>(out)[i4];
    v.x -= l; v.y -= l; v.z -= l; v.w -= l;
    reinterpret_cast<float4*>(out)[i4] = v;
  }
}

// =====================================================================
extern "C" void kernel_launch(void* const* d_in, const int* in_sizes, int n_in,
                              void* d_out, int out_size, void* d_ws, size_t ws_size,
                              hipStream_t stream)
{
  const float* x    = (const float*)d_in[0];
  const int*   ei   = (const int*)  d_in[1];
  const int*   et   = (const int*)  d_in[2];
  const float* Wrel = (const float*)d_in[3];
  const float* W0   = (const float*)d_in[4];
  const float* Wg   = (const float*)d_in[5];
  const float* bg   = (const float*)d_in[6];
  const float* Ws   = (const float*)d_in[7];
  const float* bs   = (const float*)d_in[8];
  float* out = (float*)d_out;

  // ws layout (bytes): Ybf | X0H | P1 | Pg | Ps | LSE   (~12.3 MB)
  char* p = (char*)d_ws;
  unsigned short* Ybf = (unsigned short*)p;  p += (size_t)B_*YLD*2;
  unsigned short* X0H = (unsigned short*)p;  p += (size_t)B_*XLD*2;
  float*  P1  = (float*)p;                   p += (size_t)8*B_*PLD*4;
  float2* Pg  = (float2*)p;                  p += (size_t)B_*NCBG*8;
  float2* Ps  = (float2*)p;                  p += (size_t)B_*NCBS*8;
  float*  LSE = (float*)p;

  k1a_coef_y<<<B_, 256, 0, stream>>>(x, ei, et, Ybf);

  // k1b: P1[z] = Y @ [Wrel;W0] partials (z-split over 33 K-tiles)
  gemm4<0><<<2*5*8, 256, 0, stream>>>(
      Ybf, YLD, Wrel, W0, nullptr, nullptr, nullptr, nullptr,
      nullptr, nullptr, P1, 8);
  k1c_reduce<<<(B_*XLD + 255)/256, 256, 0, stream>>>(P1, 8, X0H);

  // heads: logits (+bias) -> out, per-block (max,sumexp) -> Pg/Ps
  gemm4<1><<<2*(NCBG + NCBS), 256, 0, stream>>>(
      X0H, XLD, Wg, Ws, bg, bs, out, out + (size_t)B_*NG_,
      Pg, Ps, nullptr, 0);

  k5_lse<<<2*B_, 256, 0, stream>>>(Pg, Ps, LSE);
  k4_sub<<<2048, 256, 0, stream>>>(out, LSE);
}